// Round 12
// baseline (314.681 us; speedup 1.0000x reference)
//
#include <hip/hip_runtime.h>

// Discriminator GCN: x2 = sigmoid(GCN2(sigmoid(GCN1(x)))), N=4096, E=262144.
// Layer 1 as two bf16 MFMA GEMMs (dense S built directly in bf16 via CAS-add).
// GEMM2 fuses bias+sigmoid+W2-matvec. GEMM = r5/r9 host with staging reordered
// for long leads: P1 stages all 6 early-guarded pieces (B0-B3,A0,A2 of t+1,
// 2.5-phase lead to their vmcnt(2) guard), P2 stages A1,A3 (3-phase lead to
// next P1-end vmcnt(6)). Glue = r10 consolidation; transpose stores widened.

typedef __attribute__((ext_vector_type(8))) short bf16x8;
typedef __attribute__((ext_vector_type(4))) float f32x4;

#define NN 4096
#define NT 64   // K tiles of 64

__device__ __forceinline__ unsigned f2bf(float f) {
  unsigned u = __float_as_uint(f);
  return (u + 0x7FFFu + ((u >> 16) & 1u)) >> 16;   // RNE f32 -> bf16
}

#define GLDS(g, l) __builtin_amdgcn_global_load_lds(                      \
    (const __attribute__((address_space(1))) void*)(g),                   \
    (__attribute__((address_space(3))) void*)(l), 16, 0, 0)

// ---------------- graph degree ----------------

__global__ void count_deg_kernel(const int* __restrict__ dst, int E, float* deg) {
  int e = blockIdx.x * 256 + threadIdx.x;
  if (e < E) atomicAdd(&deg[dst[e]], 1.0f);   // deg pre-zeroed; true deg = deg+1
}

// ---------------- fused prep: scatter_S | cast_x | transpose_W1 | diag ----------------

__global__ void prep_kernel(const int* __restrict__ src, const int* __restrict__ dst, int E,
                            const float* __restrict__ deg,
                            unsigned int* __restrict__ Sw, unsigned short* __restrict__ Sbf,
                            const float* __restrict__ x, unsigned short* __restrict__ Xbf,
                            const float* __restrict__ W1, unsigned short* __restrict__ W1T) {
  const int bid = blockIdx.x, tid = threadIdx.x;
  if (bid < 1024) {
    int e = bid * 256 + tid;
    if (e >= E) return;
    int s = src[e], d = dst[e];
    float val = rsqrtf(deg[s] + 1.0f) * rsqrtf(deg[d] + 1.0f);
    size_t idx = (size_t)d * NN + s;
    unsigned int* p = Sw + (idx >> 1);
    const bool hi = (idx & 1) != 0;
    unsigned old = *p, assumed;
    do {
      assumed = old;
      unsigned short cur = hi ? (unsigned short)(assumed >> 16) : (unsigned short)(assumed & 0xFFFFu);
      float f = __uint_as_float(((unsigned)cur) << 16) + val;
      unsigned short nb = (unsigned short)f2bf(f);
      unsigned nw = hi ? ((assumed & 0x0000FFFFu) | ((unsigned)nb << 16))
                       : ((assumed & 0xFFFF0000u) | (unsigned)nb);
      old = atomicCAS(p, assumed, nw);
    } while (old != assumed);
  } else if (bid < 9216) {
    int i = ((bid - 1024) * 256 + tid) * 8;
    const float4* p = (const float4*)(x + i);
    float4 a = p[0], b = p[1];
    uint4 o;
    o.x = f2bf(a.x) | (f2bf(a.y) << 16);
    o.y = f2bf(a.z) | (f2bf(a.w) << 16);
    o.z = f2bf(b.x) | (f2bf(b.y) << 16);
    o.w = f2bf(b.z) | (f2bf(b.w) << 16);
    *(uint4*)(Xbf + i) = o;
  } else if (bid < 13312) {
    __shared__ float tile[64][65];
    const int t = bid - 9216;
    const int bx = (t & 63) * 64, by = (t >> 6) * 64;
    const int tx = tid & 63, ty = tid >> 6;      // 64 x 4
#pragma unroll
    for (int i = 0; i < 64; i += 4)
      tile[ty + i][tx] = W1[(size_t)(by + ty + i) * NN + bx + tx];
    __syncthreads();
    const int wtx = tid & 7, wty = tid >> 3;     // 8 lanes x 8 cols, 32 rows
#pragma unroll
    for (int i = 0; i < 64; i += 32) {
      int r = wty + i;                            // output row = orig col
      unsigned v[8];
#pragma unroll
      for (int j = 0; j < 8; ++j) v[j] = f2bf(tile[8 * wtx + j][r]);
      uint4 o;
      o.x = v[0] | (v[1] << 16);
      o.y = v[2] | (v[3] << 16);
      o.z = v[4] | (v[5] << 16);
      o.w = v[6] | (v[7] << 16);
      *(uint4*)(W1T + (size_t)(bx + r) * NN + by + 8 * wtx) = o;
    }
  } else {
    int v = (bid - 13312) * 256 + tid;
    if (v < NN) Sbf[(size_t)v * NN + v] = (unsigned short)f2bf(1.0f / (deg[v] + 1.0f));
  }
}

// ------------- 256x256 bf16 GEMM: C[M][N] = A[M][K] * BT[N][K]^T -------------
// LDS per buf (64KB): A [256][64] bf16 rows 128B with 16B-granule XOR swizzle; B at +32KB.
// Pieces (64 rows = 8KB): A0..A3, B0..B3. Staging of t+1: P1: B0-B3,A0,A2 (6)  P2: A1,A3.
// Guards: P1-end vmcnt(6) [A1,A3(t), staged t-1.P2, 3-phase lead];
//         P3-end lgkmcnt(0)+vmcnt(2)+barrier [6 early of t+1, staged t.P1, 2.5-phase lead].
// P4 preloads next tile's P1 frags before its MFMAs. Math: mfma_f32_16x16x32_bf16.

template <int EPI>  // 0: bf16 C store; 1: fused sigmoid(acc+b1)*W2 -> atomic h2
__global__ __launch_bounds__(512, 2) void gemm256_kernel(
    const unsigned short* __restrict__ A, const unsigned short* __restrict__ BT,
    unsigned short* __restrict__ C, const float* __restrict__ bias,
    const float* __restrict__ W2, float* __restrict__ h2) {
  __shared__ __align__(16) char smem[131072];
  const int tid = threadIdx.x;
  const int lane = tid & 63, wid = tid >> 6;
  const int wr = wid >> 2, wc = wid & 3;     // 2x4 wave grid; wave owns 128x64 of C

  const int bid = blockIdx.x;
  const int swz = (bid & 7) * 32 + (bid >> 3);   // XCD-aware remap (256 = 8*32)
  const int rowBase = (swz >> 4) * 256;
  const int colBase = (swz & 15) * 256;

  const int srow = tid >> 3;                              // 0..63 within a piece
  const int scolb = ((tid & 7) << 4) ^ ((srow & 7) << 4);
  const unsigned short* pA = A + (size_t)(rowBase + srow) * NN + (scolb >> 1);
  const unsigned short* pB = BT + (size_t)(colBase + srow) * NN + (scolb >> 1);

  const int rl = lane & 15;
  const int c0 = ((lane >> 4) << 4) ^ ((lane & 7) << 4);  // kk=0 physical col byte
  const int c1 = c0 ^ 64;                                  // kk=1
  const int aoff = (wr * 128 + rl) * 128;          // A row byte base (mh0,m=0)
  const int boff = 32768 + (wc * 64 + rl) * 128;   // B row byte base

  f32x4 acc[8][4] = {};
  bf16x8 bk0[4], bk1[4], afA[4], afB[4];

  // prologue: stage tile0 -> buf0 (A-odd last), preload P1 frags
  {
    char* w0 = smem + (wid << 10);
    GLDS(pB + (size_t)0 * 64 * NN, w0 + 32768 + 0 * 8192);
    GLDS(pB + (size_t)1 * 64 * NN, w0 + 32768 + 1 * 8192);
    GLDS(pB + (size_t)2 * 64 * NN, w0 + 32768 + 2 * 8192);
    GLDS(pB + (size_t)3 * 64 * NN, w0 + 32768 + 3 * 8192);
    GLDS(pA + (size_t)0 * 64 * NN, w0 + 0 * 8192);
    GLDS(pA + (size_t)2 * 64 * NN, w0 + 2 * 8192);
    GLDS(pA + (size_t)1 * 64 * NN, w0 + 1 * 8192);
    GLDS(pA + (size_t)3 * 64 * NN, w0 + 3 * 8192);
    asm volatile("s_waitcnt vmcnt(2)" ::: "memory");
    __builtin_amdgcn_s_barrier();
#pragma unroll
    for (int m = 0; m < 4; ++m) afA[m] = *(const bf16x8*)(smem + aoff + m * 2048 + c0);
#pragma unroll
    for (int n = 0; n < 4; ++n) bk0[n] = *(const bf16x8*)(smem + boff + n * 2048 + c0);
  }

#pragma unroll 2
  for (int t = 0; t < NT; ++t) {
    const char* lb = smem + ((t & 1) << 16);
    char* st = smem + (((t & 1) ^ 1) << 16) + (wid << 10);
    // t=NT-1 stages one tile past the operand end: lands in adjacent workspace
    // regions (audited in kernel_launch), never consumed.
    const unsigned short* s1A = pA + (size_t)(t + 1) * 64;
    const unsigned short* s1B = pB + (size_t)(t + 1) * 64;

    // ---- P1: MFMA(mh0,k0) on afA,bk0; prefetch P2 frags; stage B0-B3,A0,A2(t+1) ----
    GLDS(s1B + (size_t)0 * 64 * NN, st + 32768 + 0 * 8192);
    GLDS(s1B + (size_t)1 * 64 * NN, st + 32768 + 1 * 8192);
    GLDS(s1B + (size_t)2 * 64 * NN, st + 32768 + 2 * 8192);
    GLDS(s1B + (size_t)3 * 64 * NN, st + 32768 + 3 * 8192);
    GLDS(s1A + (size_t)0 * 64 * NN, st + 0 * 8192);
    GLDS(s1A + (size_t)2 * 64 * NN, st + 2 * 8192);
#pragma unroll
    for (int m = 0; m < 4; ++m) afB[m] = *(const bf16x8*)(lb + aoff + m * 2048 + c1);
#pragma unroll
    for (int n = 0; n < 4; ++n) bk1[n] = *(const bf16x8*)(lb + boff + n * 2048 + c1);
    __builtin_amdgcn_s_setprio(1);
#pragma unroll
    for (int m = 0; m < 4; ++m)
#pragma unroll
      for (int n = 0; n < 4; ++n)
        acc[m][n] = __builtin_amdgcn_mfma_f32_16x16x32_bf16(afA[m], bk0[n], acc[m][n], 0, 0, 0);
    __builtin_amdgcn_s_setprio(0);
    asm volatile("s_waitcnt vmcnt(6)" ::: "memory");   // A1,A3(t) landed (staged t-1.P2)
    __builtin_amdgcn_sched_barrier(0);

    // ---- P2: MFMA(mh0,k1) on afB,bk1; prefetch P3 frags; stage A1,A3(t+1) ----
    GLDS(s1A + (size_t)1 * 64 * NN, st + 1 * 8192);
    GLDS(s1A + (size_t)3 * 64 * NN, st + 3 * 8192);
#pragma unroll
    for (int m = 0; m < 4; ++m) afA[m] = *(const bf16x8*)(lb + aoff + (4 + m) * 2048 + c0);
    __builtin_amdgcn_s_setprio(1);
#pragma unroll
    for (int m = 0; m < 4; ++m)
#pragma unroll
      for (int n = 0; n < 4; ++n)
        acc[m][n] = __builtin_amdgcn_mfma_f32_16x16x32_bf16(afB[m], bk1[n], acc[m][n], 0, 0, 0);
    __builtin_amdgcn_s_setprio(0);
    __builtin_amdgcn_sched_barrier(0);

    // ---- P3: MFMA(mh1,k0) on afA,bk0; prefetch P4 frags; tile-end sync HERE ----
#pragma unroll
    for (int m = 0; m < 4; ++m) afB[m] = *(const bf16x8*)(lb + aoff + (4 + m) * 2048 + c1);
    __builtin_amdgcn_s_setprio(1);
#pragma unroll
    for (int m = 0; m < 4; ++m)
#pragma unroll
      for (int n = 0; n < 4; ++n)
        acc[4 + m][n] = __builtin_amdgcn_mfma_f32_16x16x32_bf16(afA[m], bk0[n], acc[4 + m][n], 0, 0, 0);
    __builtin_amdgcn_s_setprio(0);
    asm volatile("s_waitcnt lgkmcnt(0)" ::: "memory");  // wave's lb reads retired
    asm volatile("s_waitcnt vmcnt(2)" ::: "memory");    // 6 early pieces of t+1 landed
    __builtin_amdgcn_s_barrier();                       // buf reuse fence (1 per tile)
    __builtin_amdgcn_sched_barrier(0);

    // ---- P4: preload next tile's P1 frags (lands under MFMAs); MFMA(mh1,k1) ----
    {
      const char* nb = smem + (((t + 1) & 1) << 16);
#pragma unroll
      for (int m = 0; m < 4; ++m) afA[m] = *(const bf16x8*)(nb + aoff + m * 2048 + c0);
#pragma unroll
      for (int n = 0; n < 4; ++n) bk0[n] = *(const bf16x8*)(nb + boff + n * 2048 + c0);
    }
    __builtin_amdgcn_s_setprio(1);
#pragma unroll
    for (int m = 0; m < 4; ++m)
#pragma unroll
      for (int n = 0; n < 4; ++n)
        acc[4 + m][n] = __builtin_amdgcn_mfma_f32_16x16x32_bf16(afB[m], bk1[n], acc[4 + m][n], 0, 0, 0);
    __builtin_amdgcn_s_setprio(0);
    __builtin_amdgcn_sched_barrier(0);
  }

  // ---- epilogue ----
  const int orow = rowBase + wr * 128 + (lane >> 4) * 4;
  const int ocol = colBase + wc * 64 + (lane & 15);
  if (EPI == 0) {
#pragma unroll
    for (int n = 0; n < 4; ++n) {
      int ccol = ocol + n * 16;
#pragma unroll
      for (int m = 0; m < 8; ++m) {
#pragma unroll
        for (int i = 0; i < 4; ++i) {
          C[(size_t)(orow + m * 16 + i) * NN + ccol] = (unsigned short)f2bf(acc[m][n][i]);
        }
      }
    }
  } else {
    // x1 = sigmoid(acc + b1[col]); h2[row] += sum_col x1*W2[col]
    float bv[4], wv[4];
#pragma unroll
    for (int n = 0; n < 4; ++n) { bv[n] = bias[ocol + n * 16]; wv[n] = W2[ocol + n * 16]; }
#pragma unroll
    for (int m = 0; m < 8; ++m) {
#pragma unroll
      for (int i = 0; i < 4; ++i) {
        float s = 0.0f;
#pragma unroll
        for (int n = 0; n < 4; ++n) {
          float x = 1.0f / (1.0f + __expf(-(acc[m][n][i] + bv[n])));
          s += x * wv[n];
        }
        s += __shfl_xor(s, 1);
        s += __shfl_xor(s, 2);
        s += __shfl_xor(s, 4);
        s += __shfl_xor(s, 8);
        if ((lane & 15) == 0) atomicAdd(&h2[orow + m * 16 + i], s);
      }
    }
  }
}

// ---------------- layer 2 tail ----------------

__global__ void scatter_t_kernel(const int* __restrict__ src, const int* __restrict__ dst,
                                 int E, const float* __restrict__ deg,
                                 const float* __restrict__ h2, float* __restrict__ tacc) {
  int e = blockIdx.x * 256 + threadIdx.x;
  if (e < E) {
    int s = src[e], d = dst[e];
    atomicAdd(&tacc[d], rsqrtf(deg[s] + 1.0f) * rsqrtf(deg[d] + 1.0f) * h2[s]);
  }
}

__global__ void final_kernel(const float* __restrict__ tacc, const float* __restrict__ deg,
                             const float* __restrict__ h2, const float* __restrict__ b2,
                             float* __restrict__ out) {
  int v = blockIdx.x * 256 + threadIdx.x;
  if (v < NN) {
    float tv = tacc[v] + h2[v] / (deg[v] + 1.0f) + b2[0];
    out[v] = 1.0f / (1.0f + __expf(-tv));
  }
}

// ---------------- launch ----------------

extern "C" void kernel_launch(void* const* d_in, const int* in_sizes, int n_in,
                              void* d_out, int out_size, void* d_ws, size_t ws_size,
                              hipStream_t stream) {
  const float* x  = (const float*)d_in[0];
  const int*   ei = (const int*)d_in[1];
  const float* W1 = (const float*)d_in[2];
  const float* b1 = (const float*)d_in[3];
  const float* W2 = (const float*)d_in[4];
  const float* b2 = (const float*)d_in[5];
  float* out = (float*)d_out;
  const int E = in_sizes[1] / 2;
  const int* esrc = ei;
  const int* edst = ei + E;

  char* w = (char*)d_ws;
  unsigned short* H1T = (unsigned short*)w;                         // [0,32M)
  unsigned short* W1T = (unsigned short*)(w + (size_t)(32u << 20)); // [32M,64M)
  unsigned short* Sbf = (unsigned short*)(w + (size_t)(64u << 20)); // [64M,96M) bf16 S
  unsigned short* Xbf = (unsigned short*)(w + (size_t)(96u << 20)); // [96M,128M)
  float* deg  = (float*)(w + (size_t)(128u << 20));   // [0,16K)
  float* h2   = deg + 4096;                            // [16K,32K)
  float* tacc = deg + 8192;                            // [32K,48K)

  // zero: deg/h2/tacc (one 48KB memset) + S (32MB)
  hipMemsetAsync(deg, 0, 3 * 4096 * sizeof(float), stream);
  hipMemsetAsync(Sbf, 0, (size_t)32 << 20, stream);

  // degree count (true degree = deg+1, folded into consumers)
  count_deg_kernel<<<(E + 255) / 256, 256, 0, stream>>>(edst, E, deg);

  // fused prep: scatter_S | cast_x | transpose_W1 | diag
  prep_kernel<<<13328, 256, 0, stream>>>(esrc, edst, E, deg, (unsigned int*)Sbf, Sbf,
                                         x, Xbf, W1, W1T);

  // layer 1: GEMM1 (H1T), then GEMM2 with fused sigmoid + W2 matvec -> h2
  gemm256_kernel<0><<<256, 512, 0, stream>>>(W1T, Xbf, H1T, nullptr, nullptr, nullptr);
  gemm256_kernel<1><<<256, 512, 0, stream>>>(Sbf, H1T, nullptr, b1, W2, h2);

  // layer 2 tail: edge aggregation + final sigmoid (diag term folded in)
  scatter_t_kernel<<<(E + 255) / 256, 256, 0, stream>>>(esrc, edst, E, deg, h2, tacc);
  final_kernel<<<16, 256, 0, stream>>>(tacc, deg, h2, b2, out);
}

// Round 13
// 310.821 us; speedup vs baseline: 1.0124x; 1.0124x over previous
//
#include <hip/hip_runtime.h>

// Discriminator GCN: x2 = sigmoid(GCN2(sigmoid(GCN1(x)))), N=4096, E=262144.
// Layer 1 as two bf16 MFMA GEMMs (dense S built directly in bf16 via CAS-add).
// GEMM2 fuses bias+sigmoid+W2-matvec. GEMM = r11 kernel verbatim (best measured:
// r5 host, staging P1:B012 P2:B3,A0,A2 P3:A1,A3, barrier at P3-end, P4 preload).
// Glue = r10 consolidation + r12 widened transpose stores.

typedef __attribute__((ext_vector_type(8))) short bf16x8;
typedef __attribute__((ext_vector_type(4))) float f32x4;

#define NN 4096
#define NT 64   // K tiles of 64

__device__ __forceinline__ unsigned f2bf(float f) {
  unsigned u = __float_as_uint(f);
  return (u + 0x7FFFu + ((u >> 16) & 1u)) >> 16;   // RNE f32 -> bf16
}

#define GLDS(g, l) __builtin_amdgcn_global_load_lds(                      \
    (const __attribute__((address_space(1))) void*)(g),                   \
    (__attribute__((address_space(3))) void*)(l), 16, 0, 0)

// ---------------- graph degree ----------------

__global__ void count_deg_kernel(const int* __restrict__ dst, int E, float* deg) {
  int e = blockIdx.x * 256 + threadIdx.x;
  if (e < E) atomicAdd(&deg[dst[e]], 1.0f);   // deg pre-zeroed; true deg = deg+1
}

// ---------------- fused prep: scatter_S | cast_x | transpose_W1 | diag ----------------

__global__ void prep_kernel(const int* __restrict__ src, const int* __restrict__ dst, int E,
                            const float* __restrict__ deg,
                            unsigned int* __restrict__ Sw, unsigned short* __restrict__ Sbf,
                            const float* __restrict__ x, unsigned short* __restrict__ Xbf,
                            const float* __restrict__ W1, unsigned short* __restrict__ W1T) {
  const int bid = blockIdx.x, tid = threadIdx.x;
  if (bid < 1024) {
    int e = bid * 256 + tid;
    if (e >= E) return;
    int s = src[e], d = dst[e];
    float val = rsqrtf(deg[s] + 1.0f) * rsqrtf(deg[d] + 1.0f);
    size_t idx = (size_t)d * NN + s;
    unsigned int* p = Sw + (idx >> 1);
    const bool hi = (idx & 1) != 0;
    unsigned old = *p, assumed;
    do {
      assumed = old;
      unsigned short cur = hi ? (unsigned short)(assumed >> 16) : (unsigned short)(assumed & 0xFFFFu);
      float f = __uint_as_float(((unsigned)cur) << 16) + val;
      unsigned short nb = (unsigned short)f2bf(f);
      unsigned nw = hi ? ((assumed & 0x0000FFFFu) | ((unsigned)nb << 16))
                       : ((assumed & 0xFFFF0000u) | (unsigned)nb);
      old = atomicCAS(p, assumed, nw);
    } while (old != assumed);
  } else if (bid < 9216) {
    int i = ((bid - 1024) * 256 + tid) * 8;
    const float4* p = (const float4*)(x + i);
    float4 a = p[0], b = p[1];
    uint4 o;
    o.x = f2bf(a.x) | (f2bf(a.y) << 16);
    o.y = f2bf(a.z) | (f2bf(a.w) << 16);
    o.z = f2bf(b.x) | (f2bf(b.y) << 16);
    o.w = f2bf(b.z) | (f2bf(b.w) << 16);
    *(uint4*)(Xbf + i) = o;
  } else if (bid < 13312) {
    __shared__ float tile[64][65];
    const int t = bid - 9216;
    const int bx = (t & 63) * 64, by = (t >> 6) * 64;
    const int tx = tid & 63, ty = tid >> 6;      // 64 x 4
#pragma unroll
    for (int i = 0; i < 64; i += 4)
      tile[ty + i][tx] = W1[(size_t)(by + ty + i) * NN + bx + tx];
    __syncthreads();
    const int wtx = tid & 7, wty = tid >> 3;     // 8 lanes x 8 cols, 32 rows
#pragma unroll
    for (int i = 0; i < 64; i += 32) {
      int r = wty + i;                            // output row = orig col
      unsigned v[8];
#pragma unroll
      for (int j = 0; j < 8; ++j) v[j] = f2bf(tile[8 * wtx + j][r]);
      uint4 o;
      o.x = v[0] | (v[1] << 16);
      o.y = v[2] | (v[3] << 16);
      o.z = v[4] | (v[5] << 16);
      o.w = v[6] | (v[7] << 16);
      *(uint4*)(W1T + (size_t)(bx + r) * NN + by + 8 * wtx) = o;
    }
  } else {
    int v = (bid - 13312) * 256 + tid;
    if (v < NN) Sbf[(size_t)v * NN + v] = (unsigned short)f2bf(1.0f / (deg[v] + 1.0f));
  }
}

// ------------- 256x256 bf16 GEMM (r11 verbatim): C[M][N] = A[M][K] * BT[N][K]^T -------------
// LDS per buf (64KB): A [256][64] bf16 rows 128B with 16B-granule XOR swizzle; B at +32KB.
// Pieces (64 rows = 8KB): A0..A3, B0..B3. Staging of t+1: P1: B0,B1,B2  P2: B3,A0,A2  P3: A1,A3.
// Guards: P1-end vmcnt(3); P3-end lgkmcnt(0)+vmcnt(2)+barrier. P4 preloads next
// tile's P1 frags before its MFMAs. Math: mfma_f32_16x16x32_bf16.

template <int EPI>  // 0: bf16 C store; 1: fused sigmoid(acc+b1)*W2 -> atomic h2
__global__ __launch_bounds__(512, 2) void gemm256_kernel(
    const unsigned short* __restrict__ A, const unsigned short* __restrict__ BT,
    unsigned short* __restrict__ C, const float* __restrict__ bias,
    const float* __restrict__ W2, float* __restrict__ h2) {
  __shared__ __align__(16) char smem[131072];
  const int tid = threadIdx.x;
  const int lane = tid & 63, wid = tid >> 6;
  const int wr = wid >> 2, wc = wid & 3;     // 2x4 wave grid; wave owns 128x64 of C

  const int bid = blockIdx.x;
  const int swz = (bid & 7) * 32 + (bid >> 3);   // XCD-aware remap (256 = 8*32)
  const int rowBase = (swz >> 4) * 256;
  const int colBase = (swz & 15) * 256;

  const int srow = tid >> 3;                              // 0..63 within a piece
  const int scolb = ((tid & 7) << 4) ^ ((srow & 7) << 4);
  const unsigned short* pA = A + (size_t)(rowBase + srow) * NN + (scolb >> 1);
  const unsigned short* pB = BT + (size_t)(colBase + srow) * NN + (scolb >> 1);

  const int rl = lane & 15;
  const int c0 = ((lane >> 4) << 4) ^ ((lane & 7) << 4);  // kk=0 physical col byte
  const int c1 = c0 ^ 64;                                  // kk=1
  const int aoff = (wr * 128 + rl) * 128;          // A row byte base (mh0,m=0)
  const int boff = 32768 + (wc * 64 + rl) * 128;   // B row byte base

  f32x4 acc[8][4] = {};
  bf16x8 bk0[4], bk1[4], afA[4], afB[4];

  // prologue: stage tile0 -> buf0 (A-odd last), preload P1 frags
  {
    char* w0 = smem + (wid << 10);
    GLDS(pB + (size_t)0 * 64 * NN, w0 + 32768 + 0 * 8192);
    GLDS(pB + (size_t)1 * 64 * NN, w0 + 32768 + 1 * 8192);
    GLDS(pB + (size_t)2 * 64 * NN, w0 + 32768 + 2 * 8192);
    GLDS(pB + (size_t)3 * 64 * NN, w0 + 32768 + 3 * 8192);
    GLDS(pA + (size_t)0 * 64 * NN, w0 + 0 * 8192);
    GLDS(pA + (size_t)2 * 64 * NN, w0 + 2 * 8192);
    GLDS(pA + (size_t)1 * 64 * NN, w0 + 1 * 8192);
    GLDS(pA + (size_t)3 * 64 * NN, w0 + 3 * 8192);
    asm volatile("s_waitcnt vmcnt(2)" ::: "memory");
    __builtin_amdgcn_s_barrier();
#pragma unroll
    for (int m = 0; m < 4; ++m) afA[m] = *(const bf16x8*)(smem + aoff + m * 2048 + c0);
#pragma unroll
    for (int n = 0; n < 4; ++n) bk0[n] = *(const bf16x8*)(smem + boff + n * 2048 + c0);
  }

#pragma unroll 2
  for (int t = 0; t < NT; ++t) {
    const char* lb = smem + ((t & 1) << 16);
    char* st = smem + (((t & 1) ^ 1) << 16) + (wid << 10);
    // t=NT-1 stages one tile past the operand end: lands in adjacent workspace
    // regions (audited in kernel_launch), never consumed.
    const unsigned short* s1A = pA + (size_t)(t + 1) * 64;
    const unsigned short* s1B = pB + (size_t)(t + 1) * 64;

    // ---- P1: MFMA(mh0,k0) on afA,bk0; prefetch P2 frags; stage B012(t+1) ----
    GLDS(s1B + (size_t)0 * 64 * NN, st + 32768 + 0 * 8192);
    GLDS(s1B + (size_t)1 * 64 * NN, st + 32768 + 1 * 8192);
    GLDS(s1B + (size_t)2 * 64 * NN, st + 32768 + 2 * 8192);
#pragma unroll
    for (int m = 0; m < 4; ++m) afB[m] = *(const bf16x8*)(lb + aoff + m * 2048 + c1);
#pragma unroll
    for (int n = 0; n < 4; ++n) bk1[n] = *(const bf16x8*)(lb + boff + n * 2048 + c1);
    __builtin_amdgcn_s_setprio(1);
#pragma unroll
    for (int m = 0; m < 4; ++m)
#pragma unroll
      for (int n = 0; n < 4; ++n)
        acc[m][n] = __builtin_amdgcn_mfma_f32_16x16x32_bf16(afA[m], bk0[n], acc[m][n], 0, 0, 0);
    __builtin_amdgcn_s_setprio(0);
    asm volatile("s_waitcnt vmcnt(3)" ::: "memory");   // A-odd(t) landed
    __builtin_amdgcn_sched_barrier(0);

    // ---- P2: MFMA(mh0,k1) on afB,bk1; prefetch P3 frags; stage B3,A0,A2(t+1) ----
    GLDS(s1B + (size_t)3 * 64 * NN, st + 32768 + 3 * 8192);
    GLDS(s1A + (size_t)0 * 64 * NN, st + 0 * 8192);
    GLDS(s1A + (size_t)2 * 64 * NN, st + 2 * 8192);
#pragma unroll
    for (int m = 0; m < 4; ++m) afA[m] = *(const bf16x8*)(lb + aoff + (4 + m) * 2048 + c0);
    __builtin_amdgcn_s_setprio(1);
#pragma unroll
    for (int m = 0; m < 4; ++m)
#pragma unroll
      for (int n = 0; n < 4; ++n)
        acc[m][n] = __builtin_amdgcn_mfma_f32_16x16x32_bf16(afB[m], bk1[n], acc[m][n], 0, 0, 0);
    __builtin_amdgcn_s_setprio(0);
    __builtin_amdgcn_sched_barrier(0);

    // ---- P3: MFMA(mh1,k0) on afA,bk0; prefetch P4 frags; stage A1,A3(t+1);
    //         tile-end sync HERE (no lb reads after this phase) ----
    GLDS(s1A + (size_t)1 * 64 * NN, st + 1 * 8192);
    GLDS(s1A + (size_t)3 * 64 * NN, st + 3 * 8192);
#pragma unroll
    for (int m = 0; m < 4; ++m) afB[m] = *(const bf16x8*)(lb + aoff + (4 + m) * 2048 + c1);
    __builtin_amdgcn_s_setprio(1);
#pragma unroll
    for (int m = 0; m < 4; ++m)
#pragma unroll
      for (int n = 0; n < 4; ++n)
        acc[4 + m][n] = __builtin_amdgcn_mfma_f32_16x16x32_bf16(afA[m], bk0[n], acc[4 + m][n], 0, 0, 0);
    __builtin_amdgcn_s_setprio(0);
    asm volatile("s_waitcnt lgkmcnt(0)" ::: "memory");  // wave's lb reads retired
    asm volatile("s_waitcnt vmcnt(2)" ::: "memory");    // 6 early pieces of t+1 landed
    __builtin_amdgcn_s_barrier();                       // buf reuse fence (1 per tile)
    __builtin_amdgcn_sched_barrier(0);

    // ---- P4: preload next tile's P1 frags (lands under MFMAs); MFMA(mh1,k1) ----
    {
      const char* nb = smem + (((t + 1) & 1) << 16);
#pragma unroll
      for (int m = 0; m < 4; ++m) afA[m] = *(const bf16x8*)(nb + aoff + m * 2048 + c0);
#pragma unroll
      for (int n = 0; n < 4; ++n) bk0[n] = *(const bf16x8*)(nb + boff + n * 2048 + c0);
    }
    __builtin_amdgcn_s_setprio(1);
#pragma unroll
    for (int m = 0; m < 4; ++m)
#pragma unroll
      for (int n = 0; n < 4; ++n)
        acc[4 + m][n] = __builtin_amdgcn_mfma_f32_16x16x32_bf16(afB[m], bk1[n], acc[4 + m][n], 0, 0, 0);
    __builtin_amdgcn_s_setprio(0);
    __builtin_amdgcn_sched_barrier(0);
  }

  // ---- epilogue ----
  const int orow = rowBase + wr * 128 + (lane >> 4) * 4;
  const int ocol = colBase + wc * 64 + (lane & 15);
  if (EPI == 0) {
#pragma unroll
    for (int n = 0; n < 4; ++n) {
      int ccol = ocol + n * 16;
#pragma unroll
      for (int m = 0; m < 8; ++m) {
#pragma unroll
        for (int i = 0; i < 4; ++i) {
          C[(size_t)(orow + m * 16 + i) * NN + ccol] = (unsigned short)f2bf(acc[m][n][i]);
        }
      }
    }
  } else {
    // x1 = sigmoid(acc + b1[col]); h2[row] += sum_col x1*W2[col]
    float bv[4], wv[4];
#pragma unroll
    for (int n = 0; n < 4; ++n) { bv[n] = bias[ocol + n * 16]; wv[n] = W2[ocol + n * 16]; }
#pragma unroll
    for (int m = 0; m < 8; ++m) {
#pragma unroll
      for (int i = 0; i < 4; ++i) {
        float s = 0.0f;
#pragma unroll
        for (int n = 0; n < 4; ++n) {
          float x = 1.0f / (1.0f + __expf(-(acc[m][n][i] + bv[n])));
          s += x * wv[n];
        }
        s += __shfl_xor(s, 1);
        s += __shfl_xor(s, 2);
        s += __shfl_xor(s, 4);
        s += __shfl_xor(s, 8);
        if ((lane & 15) == 0) atomicAdd(&h2[orow + m * 16 + i], s);
      }
    }
  }
}

// ---------------- layer 2 tail ----------------

__global__ void scatter_t_kernel(const int* __restrict__ src, const int* __restrict__ dst,
                                 int E, const float* __restrict__ deg,
                                 const float* __restrict__ h2, float* __restrict__ tacc) {
  int e = blockIdx.x * 256 + threadIdx.x;
  if (e < E) {
    int s = src[e], d = dst[e];
    atomicAdd(&tacc[d], rsqrtf(deg[s] + 1.0f) * rsqrtf(deg[d] + 1.0f) * h2[s]);
  }
}

__global__ void final_kernel(const float* __restrict__ tacc, const float* __restrict__ deg,
                             const float* __restrict__ h2, const float* __restrict__ b2,
                             float* __restrict__ out) {
  int v = blockIdx.x * 256 + threadIdx.x;
  if (v < NN) {
    float tv = tacc[v] + h2[v] / (deg[v] + 1.0f) + b2[0];
    out[v] = 1.0f / (1.0f + __expf(-tv));
  }
}

// ---------------- launch ----------------

extern "C" void kernel_launch(void* const* d_in, const int* in_sizes, int n_in,
                              void* d_out, int out_size, void* d_ws, size_t ws_size,
                              hipStream_t stream) {
  const float* x  = (const float*)d_in[0];
  const int*   ei = (const int*)d_in[1];
  const float* W1 = (const float*)d_in[2];
  const float* b1 = (const float*)d_in[3];
  const float* W2 = (const float*)d_in[4];
  const float* b2 = (const float*)d_in[5];
  float* out = (float*)d_out;
  const int E = in_sizes[1] / 2;
  const int* esrc = ei;
  const int* edst = ei + E;

  char* w = (char*)d_ws;
  unsigned short* H1T = (unsigned short*)w;                         // [0,32M)
  unsigned short* W1T = (unsigned short*)(w + (size_t)(32u << 20)); // [32M,64M)
  unsigned short* Sbf = (unsigned short*)(w + (size_t)(64u << 20)); // [64M,96M) bf16 S
  unsigned short* Xbf = (unsigned short*)(w + (size_t)(96u << 20)); // [96M,128M)
  float* deg  = (float*)(w + (size_t)(128u << 20));   // [0,16K)
  float* h2   = deg + 4096;                            // [16K,32K)
  float* tacc = deg + 8192;                            // [32K,48K)

  // zero: deg/h2/tacc (one 48KB memset) + S (32MB)
  hipMemsetAsync(deg, 0, 3 * 4096 * sizeof(float), stream);
  hipMemsetAsync(Sbf, 0, (size_t)32 << 20, stream);

  // degree count (true degree = deg+1, folded into consumers)
  count_deg_kernel<<<(E + 255) / 256, 256, 0, stream>>>(edst, E, deg);

  // fused prep: scatter_S | cast_x | transpose_W1 | diag
  prep_kernel<<<13328, 256, 0, stream>>>(esrc, edst, E, deg, (unsigned int*)Sbf, Sbf,
                                         x, Xbf, W1, W1T);

  // layer 1: GEMM1 (H1T), then GEMM2 with fused sigmoid + W2 matvec -> h2
  gemm256_kernel<0><<<256, 512, 0, stream>>>(W1T, Xbf, H1T, nullptr, nullptr, nullptr);
  gemm256_kernel<1><<<256, 512, 0, stream>>>(Sbf, H1T, nullptr, b1, W2, h2);

  // layer 2 tail: edge aggregation + final sigmoid (diag term folded in)
  scatter_t_kernel<<<(E + 255) / 256, 256, 0, stream>>>(esrc, edst, E, deg, h2, tacc);
  final_kernel<<<16, 256, 0, stream>>>(tacc, deg, h2, b2, out);
}